// Round 1
// baseline (866.636 us; speedup 1.0000x reference)
//
#include <hip/hip_runtime.h>
#include <hip/hip_bf16.h>
#include <math.h>

// Problem constants (from reference)
#define VOC 50000
#define DIM 128
#define B   256
#define CTX 8
#define K   10

#define NVEC (VOC / 4)          // 12500 float4 per one-hot row
#define N_VO  (B)               // 256 rows
#define N_VI  (B * CTX)         // 2048 rows
#define N_NEG (B * K)           // 2560 rows
#define NROW  (N_VO + N_VI + N_NEG)  // 4864 rows

// ---------------------------------------------------------------------------
// Kernel 1: find the index of the single nonzero in each one-hot row.
// One block (256 threads) per row. float4 loads, 1024-float4 (16 KB) chunks,
// block-uniform early exit via a shared "found" flag: expected read ~57% of
// the 973 MB of one-hot data.
// ---------------------------------------------------------------------------
__global__ __launch_bounds__(256) void find_indices(
    const float* __restrict__ vo,
    const float* __restrict__ vi,
    const float* __restrict__ neg,
    int* __restrict__ out_idx)
{
    const int r = blockIdx.x;
    const float* row;
    if (r < N_VO)              row = vo  + (size_t)r * VOC;
    else if (r < N_VO + N_VI)  row = vi  + (size_t)(r - N_VO) * VOC;
    else                       row = neg + (size_t)(r - N_VO - N_VI) * VOC;

    const float4* row4 = (const float4*)row;

    __shared__ int found;
    if (threadIdx.x == 0) found = -1;
    __syncthreads();

    // 13 chunks max: 12 full (1024 vec4) + 1 partial (212 vec4)
    for (int start = 0; start < NVEC; start += 256 * 4) {
#pragma unroll
        for (int j = 0; j < 4; ++j) {
            const int p = start + j * 256 + (int)threadIdx.x;
            if (p < NVEC) {
                const float4 v = row4[p];
                if (v.x != 0.f || v.y != 0.f || v.z != 0.f || v.w != 0.f) {
                    int lane_off = (v.x != 0.f) ? 0 : (v.y != 0.f) ? 1
                                 : (v.z != 0.f) ? 2 : 3;
                    found = 4 * p + lane_off;   // exactly one writer per row
                }
            }
        }
        __syncthreads();               // makes `found` visible + uniform
        if (found >= 0) break;         // block-uniform branch
        // (no extra barrier needed: nobody writes `found` once it's set,
        //  and if it's still -1 nobody wrote at all)
    }

    if (threadIdx.x == 0) out_idx[r] = found;
}

// ---------------------------------------------------------------------------
// Kernel 2: per-batch-row loss. One wave (64 threads) per b; thread t owns
// dims t and t+64. 11 wave-shuffle dot reductions per block, then a single
// atomicAdd of -(left+right)/B into d_out[0].
// ---------------------------------------------------------------------------
__device__ __forceinline__ float wave_sum(float v) {
#pragma unroll
    for (int o = 32; o > 0; o >>= 1) v += __shfl_down(v, o);
    return v;   // valid in lane 0
}

__device__ __forceinline__ float log_sigmoid(float x) {
    // stable: min(x,0) - log1p(exp(-|x|))
    return fminf(x, 0.f) - log1pf(expf(-fabsf(x)));
}

__global__ __launch_bounds__(64) void cbow_loss(
    const float* __restrict__ V,
    const float* __restrict__ U,
    const int* __restrict__ idx_all,
    float* __restrict__ out)
{
    const int b = blockIdx.x;     // 0..255
    const int t = threadIdx.x;    // 0..63

    const int* idx_vo  = idx_all;
    const int* idx_vi  = idx_all + N_VO;
    const int* idx_neg = idx_all + N_VO + N_VI;

    const int vo_i = max(idx_vo[b], 0);
    const float v0 = V[(size_t)vo_i * DIM + t];
    const float v1 = V[(size_t)vo_i * DIM + t + 64];

    float e0 = 0.f, e1 = 0.f;
#pragma unroll
    for (int c = 0; c < CTX; ++c) {
        const int u = max(idx_vi[b * CTX + c], 0);
        e0 += U[(size_t)u * DIM + t];
        e1 += U[(size_t)u * DIM + t + 64];
    }
    e0 *= (1.f / CTX);
    e1 *= (1.f / CTX);

    const float dot_pos = wave_sum(v0 * e0 + v1 * e1);

    float right = 0.f;
#pragma unroll
    for (int k = 0; k < K; ++k) {
        const int u = max(idx_neg[b * K + k], 0);
        const float s = wave_sum(v0 * U[(size_t)u * DIM + t] +
                                 v1 * U[(size_t)u * DIM + t + 64]);
        if (t == 0) right += log_sigmoid(-s);
    }

    if (t == 0) {
        const float left = log_sigmoid(dot_pos);
        atomicAdd(out, -(left + right) * (1.f / B));
    }
}

// ---------------------------------------------------------------------------
// Launch
// ---------------------------------------------------------------------------
extern "C" void kernel_launch(void* const* d_in, const int* in_sizes, int n_in,
                              void* d_out, int out_size, void* d_ws, size_t ws_size,
                              hipStream_t stream) {
    const float* vo  = (const float*)d_in[0];   // [B, VOC]
    const float* vi  = (const float*)d_in[1];   // [B, CTX, VOC]
    const float* neg = (const float*)d_in[2];   // [B, K, VOC]
    const float* V   = (const float*)d_in[3];   // [VOC, DIM]
    const float* U   = (const float*)d_in[4];   // [VOC, DIM]
    float* out = (float*)d_out;

    int* idx_ws = (int*)d_ws;                   // NROW ints = 19456 B

    // d_out is poisoned with 0xAA before every timed launch; zero it (async,
    // graph-capture safe).
    hipMemsetAsync(out, 0, sizeof(float), stream);

    find_indices<<<NROW, 256, 0, stream>>>(vo, vi, neg, idx_ws);
    cbow_loss<<<B, 64, 0, stream>>>(V, U, idx_ws, out);
}